// Round 1
// 1238.336 us; speedup vs baseline: 1.0193x; 1.0193x over previous
//
#include <hip/hip_runtime.h>
#include <hip/hip_bf16.h>

typedef short short8 __attribute__((ext_vector_type(8)));
typedef float floatx4 __attribute__((ext_vector_type(4)));
typedef unsigned short ushort_t;

// Problem constants
#define NB   4
#define NC_X 64     // x channels == out channels (DIM)
#define NC_C 128    // context channels
#define ND   64
#define NHW  4096   // H*W
#define NH   64
#define NW   64
#define NS   (NB * ND)   // 256 (b,d) slices total

// f32 -> bf16 round-to-nearest-even (inputs finite)
__device__ __forceinline__ ushort_t f2bf(float f) {
    unsigned u;
    __builtin_memcpy(&u, &f, 4);
    u += 0x7fffu + ((u >> 16) & 1u);
    return (ushort_t)(u >> 16);
}

// ---------------------------------------------------------------------------
// prep: convert weights to bf16 (fold softmax scale 1/8 into wq,bq), stash in ws
// wW layout: [0,4096) = wq[oc][ic] (64x64, scaled)
//            [4096, 20480) = wkv[row][ic] (128x128): rows 0..63 = wk, 64..127 = wv
// wB: f32 [192]: bq*0.125 | bk | bv
// ---------------------------------------------------------------------------
__global__ void prep_kernel(const float* __restrict__ wq, const float* __restrict__ bq,
                            const float* __restrict__ wk, const float* __restrict__ bk,
                            const float* __restrict__ wv, const float* __restrict__ bv,
                            ushort_t* __restrict__ wW, float* __restrict__ wB) {
    int t = blockIdx.x * blockDim.x + threadIdx.x;
    int N = gridDim.x * blockDim.x;
    for (int i = t; i < 4096; i += N) wW[i] = f2bf(wq[i] * 0.125f);
    for (int i = t; i < 8192; i += N) wW[4096 + i] = f2bf(wk[i]);
    for (int i = t; i < 8192; i += N) wW[12288 + i] = f2bf(wv[i]);
    for (int i = t; i < 64; i += N) {
        wB[i] = bq[i] * 0.125f;
        wB[64 + i] = bk[i];
        wB[128 + i] = bv[i];
    }
}

// ---------------------------------------------------------------------------
// proj: per-voxel channel GEMM producing Q,K,V (bf16) for slice s = s0+blockIdx.y
// where s = b*64 + d. Block: 256 thr, handles one (slice, hw-chunk of 128).
// Grid (32, w). qws/kws/vws layout: [(oc*w + si)*4096 + hw], bf16
// ---------------------------------------------------------------------------
__global__ __launch_bounds__(256, 2)
void proj_kernel(const float* __restrict__ x, const float* __restrict__ ctx,
                 const ushort_t* __restrict__ wW, const float* __restrict__ wB,
                 ushort_t* __restrict__ qws, ushort_t* __restrict__ kws,
                 ushort_t* __restrict__ vws, int s0, int nd) {
    // K-major staging: Xs[hw][ic], Cs[hw][ic]; pads (72/136) keep bank load spread
    __shared__ ushort_t Xs[128][72];
    __shared__ ushort_t Cs[128][136];

    const int t = threadIdx.x;
    const int chunk = blockIdx.x;
    const int si = blockIdx.y;          // index within this launch window
    const int s = s0 + si;              // global slice
    const int b = s >> 6;
    const int d = s & 63;
    const int hw0 = chunk * 128;

    const float* xb = x + ((size_t)(b * NC_X) * ND + d) * NHW + hw0;   // + ic*ND*NHW + hw
    const float* cb = ctx + ((size_t)(b * NC_C) * ND + d) * NHW + hw0;

    // ---- stage X (64ic x 128hw) and CTX (128ic x 128hw), transposed, as bf16
    {
        const int hw = t & 127;
        const int icg0 = (t >> 7) * 4;     // X: 8 ic-groups total, 4 per half
        #pragma unroll
        for (int i = 0; i < 4; ++i) {
            const int ic = (icg0 + i) * 8;
            short8 v;
            #pragma unroll
            for (int j = 0; j < 8; ++j)
                v[j] = (short)f2bf(xb[(size_t)(ic + j) * (ND * NHW) + hw]);
            *(short8*)&Xs[hw][ic] = v;
        }
        const int icg0c = (t >> 7) * 8;    // CTX: 16 ic-groups total, 8 per half
        #pragma unroll
        for (int i = 0; i < 8; ++i) {
            const int ic = (icg0c + i) * 8;
            short8 v;
            #pragma unroll
            for (int j = 0; j < 8; ++j)
                v[j] = (short)f2bf(cb[(size_t)(ic + j) * (ND * NHW) + hw]);
            *(short8*)&Cs[hw][ic] = v;
        }
    }
    __syncthreads();

    const int wv = t >> 6, lane = t & 63, l15 = lane & 15, quad = lane >> 4;
    const floatx4 zero4 = {0.f, 0.f, 0.f, 0.f};

    // ================= Q = Wq(64x64) * X(64x128) =================
    short8 aQ[4][2];
    #pragma unroll
    for (int mt = 0; mt < 4; ++mt)
        #pragma unroll
        for (int kk = 0; kk < 2; ++kk)
            aQ[mt][kk] = *(const short8*)&wW[(mt * 16 + l15) * 64 + kk * 32 + quad * 8];

    floatx4 acc[4][2];
    #pragma unroll
    for (int mt = 0; mt < 4; ++mt)
        #pragma unroll
        for (int n = 0; n < 2; ++n) acc[mt][n] = zero4;

    #pragma unroll
    for (int kk = 0; kk < 2; ++kk) {
        short8 bX[2];
        #pragma unroll
        for (int n = 0; n < 2; ++n)
            bX[n] = *(const short8*)&Xs[(2 * wv + n) * 16 + l15][kk * 32 + quad * 8];
        #pragma unroll
        for (int mt = 0; mt < 4; ++mt)
            #pragma unroll
            for (int n = 0; n < 2; ++n)
                acc[mt][n] = __builtin_amdgcn_mfma_f32_16x16x32_bf16(
                    aQ[mt][kk], bX[n], acc[mt][n], 0, 0, 0);
    }
    #pragma unroll
    for (int mt = 0; mt < 4; ++mt)
        #pragma unroll
        for (int n = 0; n < 2; ++n) {
            const int col = hw0 + (2 * wv + n) * 16 + l15;
            #pragma unroll
            for (int r = 0; r < 4; ++r) {
                const int oc = mt * 16 + quad * 4 + r;
                qws[((size_t)(oc * nd + si)) * NHW + col] = f2bf(acc[mt][n][r] + wB[oc]);
            }
        }

    // ================= [K;V] = Wkv(128x128) * CTX(128x128) =================
    floatx4 acc2[8][2];
    #pragma unroll
    for (int mt = 0; mt < 8; ++mt)
        #pragma unroll
        for (int n = 0; n < 2; ++n) acc2[mt][n] = zero4;

    #pragma unroll
    for (int kk = 0; kk < 4; ++kk) {
        short8 bC[2];
        #pragma unroll
        for (int n = 0; n < 2; ++n)
            bC[n] = *(const short8*)&Cs[(2 * wv + n) * 16 + l15][kk * 32 + quad * 8];
        #pragma unroll
        for (int mt = 0; mt < 8; ++mt) {
            const short8 aW =
                *(const short8*)&wW[4096 + (mt * 16 + l15) * 128 + kk * 32 + quad * 8];
            #pragma unroll
            for (int n = 0; n < 2; ++n)
                acc2[mt][n] = __builtin_amdgcn_mfma_f32_16x16x32_bf16(
                    aW, bC[n], acc2[mt][n], 0, 0, 0);
        }
    }
    #pragma unroll
    for (int mt = 0; mt < 8; ++mt)
        #pragma unroll
        for (int n = 0; n < 2; ++n) {
            const int col = hw0 + (2 * wv + n) * 16 + l15;
            #pragma unroll
            for (int r = 0; r < 4; ++r) {
                const int row = mt * 16 + quad * 4 + r;     // 0..63 = K oc, 64..127 = V oc
                const float val = acc2[mt][n][r] + wB[64 + row];
                ushort_t* dst = (row < 64) ? kws : vws;
                dst[((size_t)((row & 63) * nd + si)) * NHW + col] = f2bf(val);
            }
        }
}

// ---------------------------------------------------------------------------
// attn: per (c, si) 64x64 slice: S = Qs*K^T, softmax rows, O = P*V / l + x
// Block 256 thr; wave w owns rows [16w,16w+16). Grid (64, w).
// ---------------------------------------------------------------------------
__global__ __launch_bounds__(256, 3)
void attn_kernel(const ushort_t* __restrict__ qws, const ushort_t* __restrict__ kws,
                 const ushort_t* __restrict__ vws, const float* __restrict__ x,
                 float* __restrict__ out, int s0, int nd) {
    __shared__ ushort_t Vs[64][72];   // V transposed: Vs[w][g]
    __shared__ ushort_t Ps[64][72];   // P (unnormalized exp), row-major

    const int c = blockIdx.x, si = blockIdx.y;
    const int s = s0 + si;
    const int b = s >> 6;
    const int d = s & 63;
    const ushort_t* qp = qws + (size_t)(c * nd + si) * NHW;
    const ushort_t* kp = kws + (size_t)(c * nd + si) * NHW;
    const ushort_t* vp = vws + (size_t)(c * nd + si) * NHW;
    const float* xp = x + ((size_t)(b * NC_X + c) * ND + d) * NHW;
    float* op = out + ((size_t)(b * NC_X + c) * ND + d) * NHW;

    const int t = threadIdx.x;
    const int wv = t >> 6, lane = t & 63, l15 = lane & 15, quad = lane >> 4;

    // T14-style issue-early: residual x loads land in regs under V-staging+barrier
    float xv[4][4];
    #pragma unroll
    for (int nt = 0; nt < 4; ++nt)
        #pragma unroll
        for (int r = 0; r < 4; ++r)
            xv[nt][r] = xp[(wv * 16 + quad * 4 + r) * NW + nt * 16 + l15];

    // stage V transposed (bf16 passthrough, no conversion)
    {
        const int w = t & 63;
        const int gg0 = (t >> 6) * 2;
        #pragma unroll
        for (int i = 0; i < 2; ++i) {
            const int g = (gg0 + i) * 8;
            short8 vvv;
            #pragma unroll
            for (int j = 0; j < 8; ++j) vvv[j] = (short)vp[(g + j) * NW + w];
            *(short8*)&Vs[w][g] = vvv;
        }
    }
    __syncthreads();

    const floatx4 zero4 = {0.f, 0.f, 0.f, 0.f};

    // S = Q K^T for this wave's 16 rows (Q already carries the 1/8 scale)
    short8 aQ[2], bK[4][2];
    #pragma unroll
    for (int kk = 0; kk < 2; ++kk)
        aQ[kk] = *(const short8*)&qp[(wv * 16 + l15) * NW + kk * 32 + quad * 8];
    #pragma unroll
    for (int nt = 0; nt < 4; ++nt)
        #pragma unroll
        for (int kk = 0; kk < 2; ++kk)
            bK[nt][kk] = *(const short8*)&kp[(nt * 16 + l15) * NW + kk * 32 + quad * 8];

    floatx4 sA[4];
    #pragma unroll
    for (int nt = 0; nt < 4; ++nt) sA[nt] = zero4;
    #pragma unroll
    for (int kk = 0; kk < 2; ++kk)
        #pragma unroll
        for (int nt = 0; nt < 4; ++nt)
            sA[nt] = __builtin_amdgcn_mfma_f32_16x16x32_bf16(aQ[kk], bK[nt][kk], sA[nt], 0, 0, 0);

    // row softmax (row = wv*16 + quad*4 + r); reductions stay inside each 16-lane quad
    float linv[4];
    #pragma unroll
    for (int r = 0; r < 4; ++r) {
        float m = sA[0][r];
        #pragma unroll
        for (int nt = 1; nt < 4; ++nt) m = fmaxf(m, sA[nt][r]);
        #pragma unroll
        for (int off = 1; off < 16; off <<= 1) m = fmaxf(m, __shfl_xor(m, off, 64));
        float e[4], sum = 0.f;
        #pragma unroll
        for (int nt = 0; nt < 4; ++nt) {
            e[nt] = __expf(sA[nt][r] - m);
            sum += e[nt];
        }
        #pragma unroll
        for (int off = 1; off < 16; off <<= 1) sum += __shfl_xor(sum, off, 64);
        linv[r] = 1.0f / sum;
        const int row = wv * 16 + quad * 4 + r;
        #pragma unroll
        for (int nt = 0; nt < 4; ++nt) Ps[row][nt * 16 + l15] = f2bf(e[nt]);
    }
    __syncthreads();

    // O = P * V  (A = P rows of this wave, B = Vs)
    short8 aP[2], bV[4][2];
    #pragma unroll
    for (int kk = 0; kk < 2; ++kk)
        aP[kk] = *(const short8*)&Ps[wv * 16 + l15][kk * 32 + quad * 8];
    #pragma unroll
    for (int nt = 0; nt < 4; ++nt)
        #pragma unroll
        for (int kk = 0; kk < 2; ++kk)
            bV[nt][kk] = *(const short8*)&Vs[nt * 16 + l15][kk * 32 + quad * 8];

    floatx4 o[4];
    #pragma unroll
    for (int nt = 0; nt < 4; ++nt) o[nt] = zero4;
    #pragma unroll
    for (int kk = 0; kk < 2; ++kk)
        #pragma unroll
        for (int nt = 0; nt < 4; ++nt)
            o[nt] = __builtin_amdgcn_mfma_f32_16x16x32_bf16(aP[kk], bV[nt][kk], o[nt], 0, 0, 0);

    #pragma unroll
    for (int nt = 0; nt < 4; ++nt)
        #pragma unroll
        for (int r = 0; r < 4; ++r) {
            const int row = wv * 16 + quad * 4 + r;
            const int col = nt * 16 + l15;
            op[row * NW + col] = o[nt][r] * linv[r] + xv[nt][r];
        }
}

// ---------------------------------------------------------------------------
extern "C" void kernel_launch(void* const* d_in, const int* in_sizes, int n_in,
                              void* d_out, int out_size, void* d_ws, size_t ws_size,
                              hipStream_t stream) {
    const float* x = (const float*)d_in[0];
    const float* ctx = (const float*)d_in[1];
    const float* wq = (const float*)d_in[2];
    const float* bq = (const float*)d_in[3];
    const float* wk = (const float*)d_in[4];
    const float* bk = (const float*)d_in[5];
    const float* wv = (const float*)d_in[6];
    const float* bv = (const float*)d_in[7];
    float* out = (float*)d_out;

    // ws layout: [0,40960) bf16 weights | [40960,41728) f32 biases | [65536,...) QKV
    ushort_t* wW = (ushort_t*)d_ws;
    float* wB = (float*)((char*)d_ws + 40960);

    const size_t perSlice = 3ull * NC_X * NHW * 2;   // Q+K+V bytes per slice = 1.5 MiB
    size_t avail = (ws_size > 65536) ? ws_size - 65536 : perSlice;
    int W = (int)(avail / perSlice);
    if (W > NS) W = NS;
    if (W < 1) W = 1;

    ushort_t* qws = (ushort_t*)((char*)d_ws + 65536);
    ushort_t* kws = qws + (size_t)NC_X * W * NHW;
    ushort_t* vws = kws + (size_t)NC_X * W * NHW;

    prep_kernel<<<dim3(32), dim3(256), 0, stream>>>(wq, bq, wk, bk, wv, bv, wW, wB);

    for (int s0 = 0; s0 < NS; s0 += W) {
        const int w = (NS - s0 < W) ? (NS - s0) : W;
        proj_kernel<<<dim3(32, w), dim3(256), 0, stream>>>(
            x, ctx, wW, wB, qws, kws, vws, s0, w);
        attn_kernel<<<dim3(64, w), dim3(256), 0, stream>>>(
            qws, kws, vws, x, out, s0, w);
    }
}